// Round 9
// baseline (181.384 us; speedup 1.0000x reference)
//
#include <hip/hip_runtime.h>
#include <cstdint>
#include <cstddef>

// Problem constants (B, S, E, H, MAXLEN) = (2, 2048, 1024, 16, 2048)
constexpr int Sn = 2048;
constexpr int En = 1024;
constexpr int Bn = 2;
constexpr int Hn = 16;
constexpr int CHUNK = 32;          // R9: 32-row chunks (= one wave tile)
constexpr int NCH = Sn / CHUNK;    // 64 chunks per batch
constexpr int Mtot = Bn * Sn;      // 4096
constexpr int GCH = Mtot / CHUNK;  // 128 global chunks

typedef __bf16 bf16x8 __attribute__((ext_vector_type(8)));
typedef float  f32x4  __attribute__((ext_vector_type(4)));

#define GLOBAL_AS(p) ((const __attribute__((address_space(1))) void*)(p))
#define LDS_AS(p)    ((__attribute__((address_space(3))) void*)(p))

__device__ __forceinline__ unsigned short f2bf(float f) {
    union { float f; uint32_t u; } v; v.f = f;
    const uint32_t u = v.u;
    return (unsigned short)((u + 0x7fffu + ((u >> 16) & 1u)) >> 16);  // RNE
}
__device__ __forceinline__ float bf2f(unsigned short s) {
    union { uint32_t u; float f; } v; v.u = (uint32_t)s << 16; return v.f;
}

// ---------------------------------------------------------------------------
// Fused fp32 -> bf16 cast of x (XN), Wv (WN), Wo (WN) in one launch.
// ---------------------------------------------------------------------------
constexpr int XN = Bn * Sn * En;   // 4194304
constexpr int WN = En * En;        // 1048576

__global__ __launch_bounds__(256)
void cast3(const float* __restrict__ x, const float* __restrict__ Wv,
           const float* __restrict__ Wo, unsigned short* __restrict__ xb,
           unsigned short* __restrict__ Wvb, unsigned short* __restrict__ Wob)
{
    const int i = (blockIdx.x * 256 + threadIdx.x) * 4;
    const float* src; unsigned short* dst; int off;
    if (i < XN)           { src = x;  dst = xb;  off = i; }
    else if (i < XN + WN) { src = Wv; dst = Wvb; off = i - XN; }
    else                  { src = Wo; dst = Wob; off = i - XN - WN; }
    const float4 v = *(const float4*)(src + off);
    ushort4 o;
    o.x = f2bf(v.x); o.y = f2bf(v.y); o.z = f2bf(v.z); o.w = f2bf(v.w);
    *(ushort4*)(dst + off) = o;
}

// ---------------------------------------------------------------------------
// bf16 MFMA GEMM (NT) — R9: 64x64 tile for 4 blocks/CU occupancy.
// C[m,n] = sum_k A[m,k]*W[n,k] + bias[n].
// Tile 64(M) x 64(N), BK=64, 256 threads = 4 waves in 2x2, wave tile 32x32
// (2x2 grid of 16x16x32 MFMAs, 2 k-halves = 8 MFMA/wave/iter).
// Grid (16, 64) = 1024 blocks = 4 blocks/CU = 4 waves/SIMD — doubles R8's
// co-residency; m114: wave-level overlap is what absorbs barrier/load
// stalls, and R8's counters put the GEMM ~5x above its issue/LDS floor
// (latency-bound). LDS 16 KB/block, VGPR capped 128 via launch_bounds.
// Staging: global_load_lds width=16 (4 instrs/wave/iter) into
// MFMA-fragment-order LDS (1024 B chunk = 16 rows x 32 k; lane l -> row
// (l&15), k (l>>4)*8; slot l*16 B) — conflict-free b128 reads.
// XCD swizzle: id -> xcd = id&7 owns 8 contiguous row-blocks (A 1 MB) x all
// 16 col-blocks (B 2 MB) -> 3 MB working set < 4 MB per-XCD L2.
// FUSE_CSUM: wave (wr)'s 32 rows = exactly global chunk 2*by+wr (CHUNK=32);
// butterfly shuffle over kq gives exact per-chunk column sums.
// ---------------------------------------------------------------------------
template<bool APPLY_MASK, bool OUT_BF16, bool FUSE_CSUM>
__global__ __launch_bounds__(256, 4)
void gemm64(const unsigned short* __restrict__ A, const unsigned short* __restrict__ Bw,
            const float* __restrict__ bias, const int* __restrict__ mask,
            void* __restrict__ Cv, float* __restrict__ csum, int M, int N, int K)
{
    __shared__ __align__(16) unsigned short As[64 * 64];  // 8 KB
    __shared__ __align__(16) unsigned short Bs[64 * 64];  // 8 KB

    const int tid  = threadIdx.x;
    const int lane = tid & 63;
    const int wv   = tid >> 6;      // wave 0..3
    const int wr   = wv >> 1;       // wave row (0..1) -> M
    const int wc   = wv & 1;        // wave col (0..1) -> N
    // XCD-aware swizzle: grid (16, 64), id -> xcd-contiguous row-blocks.
    const int id   = blockIdx.y * 16 + blockIdx.x;
    const int xcd  = id & 7;
    const int slot = id >> 3;       // 0..127
    const int by   = xcd * 8 + (slot >> 4);   // 0..63
    const int bx   = slot & 15;
    const int bm   = by * 64;
    const int bn   = bx * 64;
    const int m16  = lane & 15;
    const int kq   = lane >> 4;     // k-quarter (staging) / row-quad (C/D)

    f32x4 acc[2][2] = {};

    // Wave wv stages A row-group wv and B row-group wv (16 rows x 64 k each).
    const unsigned short* gA = A  + (size_t)(bm + 16 * wv + m16) * K + kq * 8;
    const unsigned short* gB = Bw + (size_t)(bn + 16 * wv + m16) * K + kq * 8;
    unsigned short* lA0 = &As[(wv * 2 + 0) * 512];   // wave-uniform bases
    unsigned short* lA1 = &As[(wv * 2 + 1) * 512];
    unsigned short* lB0 = &Bs[(wv * 2 + 0) * 512];
    unsigned short* lB1 = &Bs[(wv * 2 + 1) * 512];

#pragma unroll 1
    for (int k0 = 0; k0 < K; k0 += 64) {
        __syncthreads();   // previous iteration's frag reads done
        __builtin_amdgcn_global_load_lds(GLOBAL_AS(gA + k0),      LDS_AS(lA0), 16, 0, 0);
        __builtin_amdgcn_global_load_lds(GLOBAL_AS(gA + k0 + 32), LDS_AS(lA1), 16, 0, 0);
        __builtin_amdgcn_global_load_lds(GLOBAL_AS(gB + k0),      LDS_AS(lB0), 16, 0, 0);
        __builtin_amdgcn_global_load_lds(GLOBAL_AS(gB + k0 + 32), LDS_AS(lB1), 16, 0, 0);
        __syncthreads();   // implies vmcnt(0): staging landed

        bf16x8 af[2][2], bfr[2][2];
#pragma unroll
        for (int i = 0; i < 2; ++i)
#pragma unroll
            for (int kh = 0; kh < 2; ++kh) {
                af[i][kh]  = *(const bf16x8*)&As[((2 * wr + i) * 2 + kh) * 512 + lane * 8];
                bfr[i][kh] = *(const bf16x8*)&Bs[((2 * wc + i) * 2 + kh) * 512 + lane * 8];
            }
#pragma unroll
        for (int kh = 0; kh < 2; ++kh)
#pragma unroll
            for (int i = 0; i < 2; ++i)
#pragma unroll
                for (int j = 0; j < 2; ++j)
                    acc[i][j] = __builtin_amdgcn_mfma_f32_16x16x32_bf16(af[i][kh], bfr[j][kh], acc[i][j], 0, 0, 0);
    }

    // Epilogue. C/D layout: col = lane&15, row = (lane>>4)*4 + reg.
    float colsum[2] = {0.0f, 0.0f};
#pragma unroll
    for (int i = 0; i < 2; ++i) {
        const int r0 = bm + wr * 32 + i * 16 + kq * 4;
#pragma unroll
        for (int j = 0; j < 2; ++j) {
            const int c0 = bn + wc * 32 + j * 16 + m16;
            const float bcol = bias[c0];
#pragma unroll
            for (int r = 0; r < 4; ++r) {
                const int row = r0 + r;
                float val = acc[i][j][r] + bcol;
                if (APPLY_MASK) val = (mask[row] == 0) ? 0.0f : val;
                if (FUSE_CSUM) colsum[j] += val;
                if (OUT_BF16)
                    ((unsigned short*)Cv)[(size_t)row * N + c0] = f2bf(val);
                else
                    ((float*)Cv)[(size_t)row * N + c0] = val;
            }
        }
    }

    if (FUSE_CSUM) {
        // Wave wr's 32 rows are exactly global chunk gc = 2*by + wr.
        const int gc = 2 * by + wr;
#pragma unroll
        for (int j = 0; j < 2; ++j) {
            float s = colsum[j];
            s += __shfl_xor(s, 16, 64);
            s += __shfl_xor(s, 32, 64);
            if (kq == 0)
                csum[(size_t)gc * En + bn + wc * 32 + j * 16 + m16] = s;
        }
    }
}

// ---------------------------------------------------------------------------
// combine: inline exclusive scan of csum (64 chunk sums per column) +
// within-chunk prefix + weighted combine -> opre (bf16).
// out_pre[b,i,e] = (w2*Pref[i&~1] + (i odd)*w1*vm[i-1] + w0*(T - Pref[i])) / Z
// Z = (i&~1)*w2 + (i odd)*w1 + (S-i)*w0 + 1e-8   (pre-mask normalization)
// R9: CHUNK=32 -> grid (4, 64, 2) = 512 blocks = 2/CU, serial depth 32.
// ---------------------------------------------------------------------------
__global__ __launch_bounds__(256)
void combine(const unsigned short* __restrict__ vm, const float* __restrict__ csum,
             const float* __restrict__ hier, unsigned short* __restrict__ opre)
{
    const int e = blockIdx.x * 256 + threadIdx.x;
    const int c = blockIdx.y;     // chunk within batch, 0..63
    const int b = blockIdx.z;
    const int h = e >> 6;   // dh = 64

    const float w0 = hier[((size_t)b * Hn + h) * 3 + 0];
    const float w1 = hier[((size_t)b * Hn + h) * 3 + 1] * 0.5f;
    const float w2 = hier[((size_t)b * Hn + h) * 3 + 2] * 0.25f;

    // Inline exclusive scan over this batch's 64 chunk sums (L2-hot, 512 KB).
    float run = 0.0f, T = 0.0f;
    const int g0 = b * NCH;
    for (int c2 = 0; c2 < NCH; ++c2) {
        const float v = csum[(size_t)(g0 + c2) * En + e];
        if (c2 < c) run += v;
        T += v;
    }

    float prev = 0.0f;
    const size_t base = ((size_t)b * Sn + c * CHUNK) * En + e;

    for (int t = 0; t < CHUNK; ++t) {
        const int i = c * CHUNK + t;   // chunk starts even (32c), so odd-i
        const float cur = bf2f(vm[base + (size_t)t * En]);   // prev is in-chunk
        float num, Z;
        if (i & 1) {
            num = w2 * (run - prev) + w1 * prev + w0 * (T - run);
            Z = (float)(i - 1) * w2 + w1 + (float)(Sn - i) * w0 + 1e-8f;
        } else {
            num = w2 * run + w0 * (T - run);
            Z = (float)i * w2 + (float)(Sn - i) * w0 + 1e-8f;
        }
        opre[base + (size_t)t * En] = f2bf(num / Z);
        run += cur;
        prev = cur;
    }
}

// ---------------------------------------------------------------------------
extern "C" void kernel_launch(void* const* d_in, const int* in_sizes, int n_in,
                              void* d_out, int out_size, void* d_ws, size_t ws_size,
                              hipStream_t stream)
{
    // 0:x 1:attention_mask 2:level_indices 3:Wq 4:bq 5:Wk 6:bk 7:Wv 8:bv 9:hier 10:Wo 11:bo
    const float* x    = (const float*)d_in[0];
    const int*   mask = (const int*)d_in[1];
    const float* Wv   = (const float*)d_in[7];
    const float* bv   = (const float*)d_in[8];
    const float* hier = (const float*)d_in[9];
    const float* Wo   = (const float*)d_in[10];
    const float* bo   = (const float*)d_in[11];
    float* out = (float*)d_out;

    const int M = Mtot, N = En, K = En;

    char* ws = (char*)d_ws;
    unsigned short* xb    = (unsigned short*)ws;  ws += (size_t)M * K * 2;        // 8 MB
    unsigned short* Wvb   = (unsigned short*)ws;  ws += (size_t)N * K * 2;        // 2 MB
    unsigned short* Wob   = (unsigned short*)ws;  ws += (size_t)N * K * 2;        // 2 MB
    unsigned short* vmb   = (unsigned short*)ws;  ws += (size_t)M * N * 2;        // 8 MB
    float*          csum  = (float*)ws;           ws += (size_t)GCH * En * 4;     // 512 KB
    unsigned short* opreb = (unsigned short*)ws;  ws += (size_t)M * N * 2;        // 8 MB

    dim3 threads(256);

    // Fused casts to bf16 (x, Wv, Wo)
    cast3<<<dim3((XN + 2 * WN) / 1024), threads, 0, stream>>>(x, Wv, Wo, xb, Wvb, Wob);

    dim3 gemm_grid(16, 64);   // 1024 blocks = 4 blocks/CU (swizzled in-kernel)

    // 1) vm = mask ? (x @ Wv.T + bv) : 0 (bf16) + fused per-chunk column sums
    gemm64<true, true, true><<<gemm_grid, threads, 0, stream>>>(xb, Wvb, bv, mask, vmb, csum, M, N, K);
    // 2) weighted combine (inline csum scan) -> opre (bf16)
    combine<<<dim3(En / 256, NCH, Bn), threads, 0, stream>>>(vmb, csum, hier, opreb);
    // 3) out = opre @ Wo.T + bo (fp32 out)
    gemm64<false, false, false><<<gemm_grid, threads, 0, stream>>>(opreb, Wob, bo, nullptr, out, nullptr, M, N, K);
}

// Round 10
// 180.343 us; speedup vs baseline: 1.0058x; 1.0058x over previous
//
#include <hip/hip_runtime.h>
#include <cstdint>
#include <cstddef>

// Problem constants (B, S, E, H, MAXLEN) = (2, 2048, 1024, 16, 2048)
constexpr int Sn = 2048;
constexpr int En = 1024;
constexpr int Bn = 2;
constexpr int Hn = 16;
constexpr int CHUNK = 64;
constexpr int NCH = Sn / CHUNK;    // 32 chunks per batch
constexpr int Mtot = Bn * Sn;      // 4096
constexpr int GCH = Mtot / CHUNK;  // 64 global chunks
constexpr int KB = En / 32;        // 32 k-blocks of 32

typedef __bf16 bf16x8 __attribute__((ext_vector_type(8)));
typedef float  f32x4  __attribute__((ext_vector_type(4)));

__device__ __forceinline__ unsigned short f2bf(float f) {
    union { float f; uint32_t u; } v; v.f = f;
    const uint32_t u = v.u;
    return (unsigned short)((u + 0x7fffu + ((u >> 16) & 1u)) >> 16);  // RNE
}
__device__ __forceinline__ float bf2f(unsigned short s) {
    union { uint32_t u; float f; } v; v.u = (uint32_t)s << 16; return v.f;
}

// Swizzled ("flat") layout: matrix partitioned into 16-row x 32-col blocks of
// 512 ushorts. Element (r, c) -> block (r>>4, c>>5), within-block index
// lane*8 + pos where lane = (r&15) + 16*((c>>3)&3), pos = c&7. A wave's MFMA
// fragment (16x16x32 bf16) is then the contiguous 1024 B of one block: lane l
// reads 16 B at block_base + l*16 — no LDS needed, ever.
__device__ __forceinline__ size_t swz_idx(int r, int c, int kb /*cols/32*/) {
    const int blk = (r >> 4) * kb + (c >> 5);
    return (size_t)blk * 512 + (((r & 15) + (((c >> 3) & 3) << 4)) << 3) + (c & 7);
}

// ---------------------------------------------------------------------------
// Fused fp32 -> bf16 cast of x, Wv, Wo into SWIZZLED layout, one launch.
// All three matrices have 1024 columns: r = off>>10, c = off&1023.
// Each thread: 4 consecutive c (c%4==0) -> one aligned ushort4 slot.
// ---------------------------------------------------------------------------
constexpr int XN = Bn * Sn * En;   // 4194304
constexpr int WN = En * En;        // 1048576

__global__ __launch_bounds__(256)
void cast3(const float* __restrict__ x, const float* __restrict__ Wv,
           const float* __restrict__ Wo, unsigned short* __restrict__ xb,
           unsigned short* __restrict__ Wvb, unsigned short* __restrict__ Wob)
{
    const int i = (blockIdx.x * 256 + threadIdx.x) * 4;
    const float* src; unsigned short* dst; int off;
    if (i < XN)           { src = x;  dst = xb;  off = i; }
    else if (i < XN + WN) { src = Wv; dst = Wvb; off = i - XN; }
    else                  { src = Wo; dst = Wob; off = i - XN - WN; }
    const float4 v = *(const float4*)(src + off);
    ushort4 o;
    o.x = f2bf(v.x); o.y = f2bf(v.y); o.z = f2bf(v.z); o.w = f2bf(v.w);
    const int r = off >> 10, c = off & 1023;
    *(ushort4*)(dst + swz_idx(r, c, KB)) = o;   // (c&7)∈{0,4} -> 8B-aligned
}

// ---------------------------------------------------------------------------
// bf16 MFMA GEMM (NT), flatmm style (R10): NO LDS, NO barriers.
// C[m,n] = sum_k A[m,k]*W[n,k] + bias[n]; A and W in swizzled layout.
// Tile 128(M) x 64(N), 4 waves in 2x2, wave tile 64x32 (4x2 MFMAs per
// 32-k step). K-loop = 32 steps of {6 global fragment loads + 8 MFMAs} —
// pure buffer_load⇄MFMA stream the compiler pipelines with fine-grained
// vmcnt (no shared-side-effect drain, the structural stall of R3-R9).
// Grid (16, 32) = 512 blocks; XCD swizzle keeps each XCD's A slice (1 MB) +
// B (2 MB) inside its 4 MB L2.
// ---------------------------------------------------------------------------
template<bool APPLY_MASK, bool OUT_BF16, bool FUSE_CSUM>
__global__ __launch_bounds__(256)
void gemm_flat(const unsigned short* __restrict__ A, const unsigned short* __restrict__ Bw,
               const float* __restrict__ bias, const int* __restrict__ mask,
               void* __restrict__ Cv, float* __restrict__ csum)
{
    const int tid  = threadIdx.x;
    const int lane = tid & 63;
    const int wv   = tid >> 6;      // wave 0..3
    const int wr   = wv >> 1;       // wave row (0..1) -> M
    const int wc   = wv & 1;        // wave col (0..1) -> N
    // XCD-aware swizzle: grid (16, 32); id -> xcd-contiguous row-blocks.
    const int id   = blockIdx.y * 16 + blockIdx.x;
    const int xcd  = id & 7;
    const int slot = id >> 3;
    const int by   = xcd * 4 + (slot >> 4);
    const int bx   = slot & 15;
    const int bm   = by * 128;
    const int bn   = bx * 64;
    const int m16  = lane & 15;
    const int kq   = lane >> 4;     // row-quad (C/D layout)

    f32x4 acc[4][2] = {};

    // Fragment base pointers: wave's A row-groups rb..rb+3, B col-groups cb..cb+1.
    const int rb = by * 8 + wr * 4;   // row-block (16-row) index
    const int cb = bx * 4 + wc * 2;   // col-block (16-col) index of W
    const unsigned short* aBase = A  + (size_t)rb * KB * 512 + lane * 8;
    const unsigned short* bBase = Bw + (size_t)cb * KB * 512 + lane * 8;

#pragma unroll 4
    for (int kc = 0; kc < KB; ++kc) {
        bf16x8 af0 = *(const bf16x8*)(aBase + (size_t)(0 * KB + kc) * 512);
        bf16x8 af1 = *(const bf16x8*)(aBase + (size_t)(1 * KB + kc) * 512);
        bf16x8 af2 = *(const bf16x8*)(aBase + (size_t)(2 * KB + kc) * 512);
        bf16x8 af3 = *(const bf16x8*)(aBase + (size_t)(3 * KB + kc) * 512);
        bf16x8 bf0 = *(const bf16x8*)(bBase + (size_t)(0 * KB + kc) * 512);
        bf16x8 bf1 = *(const bf16x8*)(bBase + (size_t)(1 * KB + kc) * 512);
        acc[0][0] = __builtin_amdgcn_mfma_f32_16x16x32_bf16(af0, bf0, acc[0][0], 0, 0, 0);
        acc[0][1] = __builtin_amdgcn_mfma_f32_16x16x32_bf16(af0, bf1, acc[0][1], 0, 0, 0);
        acc[1][0] = __builtin_amdgcn_mfma_f32_16x16x32_bf16(af1, bf0, acc[1][0], 0, 0, 0);
        acc[1][1] = __builtin_amdgcn_mfma_f32_16x16x32_bf16(af1, bf1, acc[1][1], 0, 0, 0);
        acc[2][0] = __builtin_amdgcn_mfma_f32_16x16x32_bf16(af2, bf0, acc[2][0], 0, 0, 0);
        acc[2][1] = __builtin_amdgcn_mfma_f32_16x16x32_bf16(af2, bf1, acc[2][1], 0, 0, 0);
        acc[3][0] = __builtin_amdgcn_mfma_f32_16x16x32_bf16(af3, bf0, acc[3][0], 0, 0, 0);
        acc[3][1] = __builtin_amdgcn_mfma_f32_16x16x32_bf16(af3, bf1, acc[3][1], 0, 0, 0);
    }

    // Epilogue. C/D layout: col = lane&15, row = (lane>>4)*4 + reg.
    float colsum[2] = {0.0f, 0.0f};
#pragma unroll
    for (int i = 0; i < 4; ++i) {
        const int r0 = bm + wr * 64 + i * 16 + kq * 4;
#pragma unroll
        for (int j = 0; j < 2; ++j) {
            const int c0 = bn + wc * 32 + j * 16 + m16;
            const float bcol = bias[c0];
#pragma unroll
            for (int r = 0; r < 4; ++r) {
                const int row = r0 + r;
                float val = acc[i][j][r] + bcol;
                if (APPLY_MASK) val = (mask[row] == 0) ? 0.0f : val;
                if (FUSE_CSUM) colsum[j] += val;
                if (OUT_BF16)
                    ((unsigned short*)Cv)[(size_t)row * En + c0] = f2bf(val);
                else
                    ((float*)Cv)[(size_t)row * En + c0] = val;
            }
        }
    }

    if (FUSE_CSUM) {
        // Wave wr's 64 rows are exactly global chunk gc = 2*by + wr.
        const int gc = 2 * by + wr;
#pragma unroll
        for (int j = 0; j < 2; ++j) {
            float s = colsum[j];
            s += __shfl_xor(s, 16, 64);
            s += __shfl_xor(s, 32, 64);
            if (kq == 0)
                csum[(size_t)gc * En + bn + wc * 32 + j * 16 + m16] = s;
        }
    }
}

// ---------------------------------------------------------------------------
// combine: inline exclusive scan of csum (32 chunk sums per column) +
// within-chunk prefix + weighted combine -> opre (bf16, SWIZZLED for gemm2).
// out_pre[b,i,e] = (w2*Pref[i&~1] + (i odd)*w1*vm[i-1] + w0*(T - Pref[i])) / Z
// Z = (i&~1)*w2 + (i odd)*w1 + (S-i)*w0 + 1e-8   (pre-mask normalization)
// ---------------------------------------------------------------------------
__global__ __launch_bounds__(256)
void combine(const unsigned short* __restrict__ vm, const float* __restrict__ csum,
             const float* __restrict__ hier, unsigned short* __restrict__ opre)
{
    const int e = blockIdx.x * 256 + threadIdx.x;
    const int c = blockIdx.y;     // chunk within batch, 0..31
    const int b = blockIdx.z;
    const int h = e >> 6;   // dh = 64

    const float w0 = hier[((size_t)b * Hn + h) * 3 + 0];
    const float w1 = hier[((size_t)b * Hn + h) * 3 + 1] * 0.5f;
    const float w2 = hier[((size_t)b * Hn + h) * 3 + 2] * 0.25f;

    // Inline exclusive scan over this batch's 32 chunk sums (L2-hot).
    float run = 0.0f, T = 0.0f;
    const int g0 = b * NCH;
    for (int c2 = 0; c2 < NCH; ++c2) {
        const float v = csum[(size_t)(g0 + c2) * En + e];
        if (c2 < c) run += v;
        T += v;
    }

    // Swizzled-store components for column e (row part varies in the loop).
    const int ecol  = (e >> 5);            // 32-col block of e
    const int elane = ((e >> 3) & 3) << 4; // 16*((e&31)>>3)
    const int epos  = e & 7;

    float prev = 0.0f;
    const size_t base = ((size_t)b * Sn + c * CHUNK) * En + e;

    for (int t = 0; t < CHUNK; ++t) {
        const int i = c * CHUNK + t;
        const float cur = bf2f(vm[base + (size_t)t * En]);
        float num, Z;
        if (i & 1) {
            num = w2 * (run - prev) + w1 * prev + w0 * (T - run);
            Z = (float)(i - 1) * w2 + w1 + (float)(Sn - i) * w0 + 1e-8f;
        } else {
            num = w2 * run + w0 * (T - run);
            Z = (float)i * w2 + (float)(Sn - i) * w0 + 1e-8f;
        }
        const int gi = b * Sn + i;   // global row
        const size_t di = (size_t)((gi >> 4) * KB + ecol) * 512
                        + ((((gi & 15) + elane)) << 3) + epos;
        opre[di] = f2bf(num / Z);
        run += cur;
        prev = cur;
    }
}

// ---------------------------------------------------------------------------
extern "C" void kernel_launch(void* const* d_in, const int* in_sizes, int n_in,
                              void* d_out, int out_size, void* d_ws, size_t ws_size,
                              hipStream_t stream)
{
    // 0:x 1:attention_mask 2:level_indices 3:Wq 4:bq 5:Wk 6:bk 7:Wv 8:bv 9:hier 10:Wo 11:bo
    const float* x    = (const float*)d_in[0];
    const int*   mask = (const int*)d_in[1];
    const float* Wv   = (const float*)d_in[7];
    const float* bv   = (const float*)d_in[8];
    const float* hier = (const float*)d_in[9];
    const float* Wo   = (const float*)d_in[10];
    const float* bo   = (const float*)d_in[11];
    float* out = (float*)d_out;

    char* ws = (char*)d_ws;
    unsigned short* xb    = (unsigned short*)ws;  ws += (size_t)Mtot * En * 2;   // 8 MB (swizzled)
    unsigned short* Wvb   = (unsigned short*)ws;  ws += (size_t)En * En * 2;     // 2 MB (swizzled)
    unsigned short* Wob   = (unsigned short*)ws;  ws += (size_t)En * En * 2;     // 2 MB (swizzled)
    unsigned short* vmb   = (unsigned short*)ws;  ws += (size_t)Mtot * En * 2;   // 8 MB (linear)
    float*          csum  = (float*)ws;           ws += (size_t)GCH * En * 4;    // 256 KB
    unsigned short* opreb = (unsigned short*)ws;  ws += (size_t)Mtot * En * 2;   // 8 MB (swizzled)

    dim3 threads(256);

    // Fused casts to bf16, swizzled (x, Wv, Wo)
    cast3<<<dim3((XN + 2 * WN) / 1024), threads, 0, stream>>>(x, Wv, Wo, xb, Wvb, Wob);

    dim3 gemm_grid(16, 32);   // 512 blocks (XCD-swizzled in-kernel)

    // 1) vm = mask ? (x @ Wv.T + bv) : 0 (bf16 linear) + fused chunk col sums
    gemm_flat<true, true, true><<<gemm_grid, threads, 0, stream>>>(xb, Wvb, bv, mask, vmb, csum);
    // 2) weighted combine (inline csum scan) -> opre (bf16, swizzled)
    combine<<<dim3(En / 256, NCH, Bn), threads, 0, stream>>>(vmb, csum, hier, opreb);
    // 3) out = opre @ Wo.T + bo (fp32 out)
    gemm_flat<false, false, false><<<gemm_grid, threads, 0, stream>>>(opreb, Wob, bo, nullptr, out, nullptr);
}